// Round 15
// baseline (911.827 us; speedup 1.0000x reference)
//
#include <hip/hip_runtime.h>
#include <math.h>

#define N_PTS 1048576

typedef _Float16 half8 __attribute__((ext_vector_type(8)));
typedef _Float16 half4v __attribute__((ext_vector_type(4)));
typedef float float4v __attribute__((ext_vector_type(4)));
typedef float f32x16 __attribute__((ext_vector_type(16)));

// ws layout (fp16 element offsets), k-tiled for coalesced A-frag loads:
//   W0   [12 kb][256 n][8 j]   k = kb*8+j (91..95 zero)       @ 0       (24576)
//   Wh   7 x [32 kb][256 n][8 j]                              @ 24576   (7*65536)
//   Whead [16 n][256 k] plain  (n=0 -> wd, 1..3 -> wc)        @ 483328  (4096)
#define W0T_OFF 0
#define WHT_OFF 24576
#define WHEAD_OFF 483328
#define WS_HALVES 487424

__global__ void prep_weights(const float* __restrict__ w0,
                             const float* __restrict__ wh,
                             const float* __restrict__ wd,
                             const float* __restrict__ wc,
                             _Float16* __restrict__ ws) {
  int stride = gridDim.x * blockDim.x;
  for (int i = blockIdx.x * blockDim.x + threadIdx.x; i < WS_HALVES; i += stride) {
    float v;
    if (i < WHT_OFF) {                        // W0 tiled [12][256][8]
      int kb = i >> 11, n = (i >> 3) & 255, j = i & 7;
      int k = kb * 8 + j;
      v = (k < 91) ? w0[k * 256 + n] : 0.0f;
    } else if (i < WHEAD_OFF) {               // Wh tiled 7x[32][256][8]
      int rel = i - WHT_OFF;
      int layer = rel >> 16;
      int r = rel & 65535;
      int kb = r >> 11, n = (r >> 3) & 255, j = r & 7;
      int k = kb * 8 + j;
      v = wh[(layer << 16) + k * 256 + n];
    } else {                                  // Whead plain [16][256]
      int rel = i - WHEAD_OFF;
      int n = rel >> 8, k = rel & 255;
      v = (n == 0) ? wd[k] : ((n < 4) ? wc[k * 3 + n - 1] : 0.0f);
    }
    ws[i] = (_Float16)v;
  }
}

// X: k-tiled LDS layout [m/32][k/8][32 m][8 k] fp16 (64 KB), then 8 KB bias.
// byte addr = (m>>5)*16384 + (k>>3)*512 + (m&31)*16 + (k&7)*2
// B-frag reads: 32 lanes contiguous 512 B -> conflict-free.
// Epilogue b64 writes: 16-lane phases at stride 16 B -> 2-way (free).
#define BIAS_LDS 65536  // [8 layer][256 n] float
__device__ __forceinline__ int x2addr(int m, int kb) {  // kb = k/8
  return (m >> 5) * 16384 + kb * 512 + (m & 31) * 16;
}

// One layer: Y[m][n] = act(sum_k W[n][k] X[m][k] + b[n]) for 128 pts.
// Swapped MFMA: A = weights (rows -> n), B = acts (cols -> m), D[n][m].
// 4 waves (1/SIMD): wave w owns n in [w*64,+64) (2 n-tiles), ALL 128 m
// (4 m-tiles). Per ks: 2 A-loads + 4 B ds_reads -> 8 MFMA, 1-deep prefetch.
// NO setprio (m190: hurts barrier-locked structures by starving the
// co-resident WG's loads). Relu in packed f16 (v_pk_max_f16): exact since
// cvt is monotone and cvt(0)=0. Bias from LDS; A ks=0 chained across layers.
template <int KB>  // KB = K/16
__device__ __forceinline__ void mlp_layer(char* X, const _Float16* __restrict__ Wt,
                                          const _Float16* __restrict__ Wt_next,
                                          size_t laneoff, int bias_off, bool relu,
                                          int wn, int lr5, int lg2,
                                          half8& a0, half8& a1) {
  const _Float16* wb = Wt + laneoff;
  const _Float16* wbn = Wt_next + laneoff;
  // B-read base: lane lr5 within k-subtile kb = 2*ks + lg2, m-subtile mt
  const int broff = lg2 * 512 + lr5 * 16;  // + mt*16384 + ks*1024

  // fill: B first (ds), bias after (ds, broadcast) -> all overlap
  half8 bc0 = *(const half8*)&X[broff];
  half8 bc1 = *(const half8*)&X[broff + 16384];
  half8 bc2 = *(const half8*)&X[broff + 32768];
  half8 bc3 = *(const half8*)&X[broff + 49152];
  float4v bq[2][4];
#pragma unroll
  for (int nt = 0; nt < 2; ++nt)
#pragma unroll
    for (int q = 0; q < 4; ++q)
      bq[nt][q] = *(const float4v*)&X[bias_off +
                                      (wn * 64 + nt * 32 + q * 8 + lg2 * 4) * 4];

  f32x16 acc[2][4];  // [nt][mt]
#pragma unroll
  for (int nt = 0; nt < 2; ++nt)
#pragma unroll
    for (int q = 0; q < 4; ++q)
#pragma unroll
      for (int mt = 0; mt < 4; ++mt)
#pragma unroll
        for (int rr = 0; rr < 4; ++rr) acc[nt][mt][q * 4 + rr] = bq[nt][q][rr];

#pragma unroll
  for (int ks = 0; ks < KB; ++ks) {
    // prefetch ks+1 (or next layer's ks=0 on the last iteration)
    const _Float16* nb = (ks + 1 < KB) ? (wb + (size_t)(ks + 1) * 4096) : wbn;
    half8 a0n = *(const half8*)nb;
    half8 a1n = *(const half8*)(nb + 256);
    half8 bn0 = bc0, bn1 = bc1, bn2 = bc2, bn3 = bc3;
    if (ks + 1 < KB) {
      const int c = broff + (ks + 1) * 1024;
      bn0 = *(const half8*)&X[c];
      bn1 = *(const half8*)&X[c + 16384];
      bn2 = *(const half8*)&X[c + 32768];
      bn3 = *(const half8*)&X[c + 49152];
    }
    acc[0][0] = __builtin_amdgcn_mfma_f32_32x32x16_f16(a0, bc0, acc[0][0], 0, 0, 0);
    acc[1][0] = __builtin_amdgcn_mfma_f32_32x32x16_f16(a1, bc0, acc[1][0], 0, 0, 0);
    acc[0][1] = __builtin_amdgcn_mfma_f32_32x32x16_f16(a0, bc1, acc[0][1], 0, 0, 0);
    acc[1][1] = __builtin_amdgcn_mfma_f32_32x32x16_f16(a1, bc1, acc[1][1], 0, 0, 0);
    acc[0][2] = __builtin_amdgcn_mfma_f32_32x32x16_f16(a0, bc2, acc[0][2], 0, 0, 0);
    acc[1][2] = __builtin_amdgcn_mfma_f32_32x32x16_f16(a1, bc2, acc[1][2], 0, 0, 0);
    acc[0][3] = __builtin_amdgcn_mfma_f32_32x32x16_f16(a0, bc3, acc[0][3], 0, 0, 0);
    acc[1][3] = __builtin_amdgcn_mfma_f32_32x32x16_f16(a1, bc3, acc[1][3], 0, 0, 0);
    a0 = a0n; a1 = a1n;
    bc0 = bn0; bc1 = bn1; bc2 = bn2; bc3 = bn3;
  }
  __syncthreads();  // all waves done reading X (also drains chained A loads)

  // Epilogue: lane holds D[n = wn*64+nt*32+8q+4lg2+rr][m = mt*32+lr5].
  // cvt to f16 first (RNE), relu as packed v_pk_max_f16 (exact: cvt monotone,
  // cvt(0)=0). 4 consecutive n (rr) = 4 consecutive k of next layer -> b64
  // write at X2[m][k=n]: addr = mt*16384 + (wn*8+nt*4+q)*512 + lr5*16 + lg2*8.
  const half4v zero4 = {(_Float16)0, (_Float16)0, (_Float16)0, (_Float16)0};
#pragma unroll
  for (int mt = 0; mt < 4; ++mt) {
#pragma unroll
    for (int nt = 0; nt < 2; ++nt)
#pragma unroll
      for (int q = 0; q < 4; ++q) {
        half4v hv;
#pragma unroll
        for (int rr = 0; rr < 4; ++rr) hv[rr] = (_Float16)acc[nt][mt][q * 4 + rr];
        if (relu) hv = __builtin_elementwise_max(hv, zero4);
        *(half4v*)&X[mt * 16384 + (wn * 8 + nt * 4 + q) * 512 + lr5 * 16 + lg2 * 8] = hv;
      }
  }
  __syncthreads();  // Y visible as next layer's X
}

__global__ __launch_bounds__(256, 2) void nerf_fused(
    const float* __restrict__ pos, const float* __restrict__ vdir,
    const float* __restrict__ t0, const float* __restrict__ t1,
    const float* __restrict__ t2, const float* __restrict__ t3,
    const float* __restrict__ t4, const float* __restrict__ t5,
    const float* __restrict__ t6, const float* __restrict__ t7,
    const float* __restrict__ b0, const float* __restrict__ bh,
    const float* __restrict__ bd, const float* __restrict__ bc,
    const _Float16* __restrict__ ws, float* __restrict__ out) {
  __shared__ __align__(16) char X[73728];  // 64 KB acts + 8 KB bias
  const int tid = threadIdx.x;
  const int wg = blockIdx.x;
  const int m = tid & 127;
  const int p = wg * 128 + m;

  const int lane = tid & 63;
  const int w = tid >> 6;  // wave 0..3 -> n in [w*64, +64)
  const int lr5 = lane & 31;
  const int lg2 = lane >> 5;
  const size_t laneoff = ((size_t)(lg2 * 256 + w * 64 + lr5)) * 8;

  // chained A preload for layer 0 (completes at the encode barrier)
  half8 a0 = *(const half8*)(ws + W0T_OFF + laneoff);
  half8 a1 = *(const half8*)(ws + W0T_OFF + laneoff + 256);

  // ---------------- encode: 128 points -> X[m][k<96] ----------------
  if (tid < 128) {
    // hash levels 0..7 for point m -> kb = lv
    const float px = pos[p * 3], py = pos[p * 3 + 1], pz = pos[p * 3 + 2];
    const float* tabs[8] = {t0, t1, t2, t3, t4, t5, t6, t7};
    const int resi[8] = {32, 64, 128, 256, 512, 1024, 2048, 2048};
    const float tmax[8] = {32767.0f, 262143.0f, 524287.0f, 524287.0f,
                           524287.0f, 524287.0f, 524287.0f, 524287.0f};
#pragma unroll
    for (int lv = 0; lv < 8; ++lv) {
      const float r = (float)resi[lv];
      const float hr = 0.5f * r;
      const float rm1 = r - 1.0f;
      // replicate numpy fp32 rounding exactly; no FMA contraction
      float cx = fminf(fmaxf(__fmul_rn(__fadd_rn(px, 1.0f), hr), 0.0f), rm1);
      float cy = fminf(fmaxf(__fmul_rn(__fadd_rn(py, 1.0f), hr), 0.0f), rm1);
      float cz = fminf(fmaxf(__fmul_rn(__fadd_rn(pz, 1.0f), hr), 0.0f), rm1);
      float idxf = __fadd_rn(__fadd_rn(__fmul_rn(cx, r * r), __fmul_rn(cy, r)), cz);
      idxf = fminf(fmaxf(idxf, 0.0f), tmax[lv]);
      int idx = (int)idxf;
      const float4* row = (const float4*)(tabs[lv] + (size_t)idx * 8);
      float4 f0 = row[0], f1 = row[1];
      half8 h;
      h[0] = (_Float16)f0.x; h[1] = (_Float16)f0.y;
      h[2] = (_Float16)f0.z; h[3] = (_Float16)f0.w;
      h[4] = (_Float16)f1.x; h[5] = (_Float16)f1.y;
      h[6] = (_Float16)f1.z; h[7] = (_Float16)f1.w;
      *(half8*)&X[x2addr(m, lv)] = h;
    }
  } else {
    // view features k = 64..90 (kb = 8..11), zero pad to 95
    float v0 = vdir[p * 3], v1 = vdir[p * 3 + 1], v2 = vdir[p * 3 + 2];
    const float cf[4] = {(float)(M_PI), (float)(2.0 * M_PI),
                         (float)(4.0 * M_PI), (float)(8.0 * M_PI)};
    float feat[32];
    feat[0] = v0; feat[1] = v1; feat[2] = v2;
    float vv[3] = {v0, v1, v2};
#pragma unroll
    for (int f = 0; f < 4; ++f)
#pragma unroll
      for (int d = 0; d < 3; ++d) {
        float arg = __fmul_rn(cf[f], vv[d]);
        feat[3 + f * 6 + d] = __sinf(arg);
        feat[6 + f * 6 + d] = __cosf(arg);
      }
#pragma unroll
    for (int i = 27; i < 32; ++i) feat[i] = 0.0f;
#pragma unroll
    for (int s = 0; s < 4; ++s) {
      half8 h;
#pragma unroll
      for (int j = 0; j < 8; ++j) h[j] = (_Float16)feat[s * 8 + j];
      *(half8*)&X[x2addr(m, 8 + s)] = h;
    }
  }
  // stage biases into LDS: [8 layer][256 n] float (b0 then bh[0..6])
#pragma unroll
  for (int i = 0; i < 8; ++i) {
    int idx = tid + i * 256;
    float bv = (idx < 256) ? b0[idx] : bh[idx - 256];
    *(float*)&X[BIAS_LDS + idx * 4] = bv;
  }
  __syncthreads();

  // ---------------- MLP ----------------
  mlp_layer<6>(X, ws + W0T_OFF, ws + WHT_OFF, laneoff, BIAS_LDS, true,
               w, lr5, lg2, a0, a1);
#pragma unroll 1
  for (int i = 0; i < 7; ++i) {
    const _Float16* wnext =
        (i < 6) ? (ws + WHT_OFF + ((i + 1) << 16)) : (ws + W0T_OFF);  // last: dummy
    mlp_layer<16>(X, ws + WHT_OFF + (i << 16), wnext, laneoff,
                  BIAS_LDS + (i + 1) * 1024, i < 6, w, lr5, lg2, a0, a1);
  }

  // ------- head (16x16x32, A = acts): wave w -> pts [w*32, +32), 2 m-tiles ----
  const int lr = lane & 15;
  const int lg = lane >> 4;
  float4v hacc[2];
  {
    float bv = (lr == 0) ? bd[0] : ((lr < 4) ? bc[lr - 1] : 0.0f);
    hacc[0] = (float4v){bv, bv, bv, bv};
    hacc[1] = hacc[0];
  }
  const _Float16* Wh = ws + WHEAD_OFF;
#pragma unroll
  for (int ks = 0; ks < 8; ++ks) {
    half8 bfr = *(const half8*)(Wh + lr * 256 + ks * 32 + lg * 8);
#pragma unroll
    for (int mt = 0; mt < 2; ++mt) {
      // A[m = w*32+mt*16+lr][k = ks*32 + lg*8 .. +7] -> kb = ks*4 + lg
      half8 a = *(const half8*)&X[x2addr(w * 32 + mt * 16 + lr, ks * 4 + lg)];
      hacc[mt] = __builtin_amdgcn_mfma_f32_16x16x32_f16(a, bfr, hacc[mt], 0, 0, 0);
    }
  }
#pragma unroll
  for (int mt = 0; mt < 2; ++mt)
#pragma unroll
    for (int r = 0; r < 4; ++r) {
      int pp = wg * 128 + w * 32 + mt * 16 + lg * 4 + r;
      float vv = hacc[mt][r];
      if (lr == 0) {
        out[pp] = vv;  // density
      } else if (lr < 4) {
        out[N_PTS + 3 * pp + (lr - 1)] = 1.0f / (1.0f + __expf(-vv));  // color
      }
    }
}

extern "C" void kernel_launch(void* const* d_in, const int* in_sizes, int n_in,
                              void* d_out, int out_size, void* d_ws, size_t ws_size,
                              hipStream_t stream) {
  const float* pos = (const float*)d_in[0];
  const float* vdir = (const float*)d_in[1];
  const float* t0 = (const float*)d_in[2];
  const float* t1 = (const float*)d_in[3];
  const float* t2 = (const float*)d_in[4];
  const float* t3 = (const float*)d_in[5];
  const float* t4 = (const float*)d_in[6];
  const float* t5 = (const float*)d_in[7];
  const float* t6 = (const float*)d_in[8];
  const float* t7 = (const float*)d_in[9];
  const float* w0 = (const float*)d_in[10];
  const float* b0 = (const float*)d_in[11];
  const float* wh = (const float*)d_in[12];
  const float* bh = (const float*)d_in[13];
  const float* wd = (const float*)d_in[14];
  const float* bd = (const float*)d_in[15];
  const float* wc = (const float*)d_in[16];
  const float* bc = (const float*)d_in[17];
  _Float16* ws = (_Float16*)d_ws;
  float* out = (float*)d_out;

  hipLaunchKernelGGL(prep_weights, dim3((WS_HALVES + 255) / 256), dim3(256), 0, stream,
                     w0, wh, wd, wc, ws);
  hipLaunchKernelGGL(nerf_fused, dim3(N_PTS / 128), dim3(256), 0, stream,
                     pos, vdir, t0, t1, t2, t3, t4, t5, t6, t7,
                     b0, bh, bd, bc, (const _Float16*)ws, out);
}

// Round 16
// 854.726 us; speedup vs baseline: 1.0668x; 1.0668x over previous
//
#include <hip/hip_runtime.h>
#include <math.h>

#define N_PTS 1048576

typedef _Float16 half8 __attribute__((ext_vector_type(8)));
typedef _Float16 half4v __attribute__((ext_vector_type(4)));
typedef float float4v __attribute__((ext_vector_type(4)));
typedef float f32x16 __attribute__((ext_vector_type(16)));

// ws layout (fp16 element offsets), k-tiled for coalesced A-frag loads:
//   W0   [12 kb][256 n][8 j]   k = kb*8+j (91..95 zero)       @ 0       (24576)
//   Wh   7 x [32 kb][256 n][8 j]                              @ 24576   (7*65536)
//   Whead [16 n][256 k] plain  (n=0 -> wd, 1..3 -> wc)        @ 483328  (4096)
#define W0T_OFF 0
#define WHT_OFF 24576
#define WHEAD_OFF 483328
#define WS_HALVES 487424

__global__ void prep_weights(const float* __restrict__ w0,
                             const float* __restrict__ wh,
                             const float* __restrict__ wd,
                             const float* __restrict__ wc,
                             _Float16* __restrict__ ws) {
  int stride = gridDim.x * blockDim.x;
  for (int i = blockIdx.x * blockDim.x + threadIdx.x; i < WS_HALVES; i += stride) {
    float v;
    if (i < WHT_OFF) {                        // W0 tiled [12][256][8]
      int kb = i >> 11, n = (i >> 3) & 255, j = i & 7;
      int k = kb * 8 + j;
      v = (k < 91) ? w0[k * 256 + n] : 0.0f;
    } else if (i < WHEAD_OFF) {               // Wh tiled 7x[32][256][8]
      int rel = i - WHT_OFF;
      int layer = rel >> 16;
      int r = rel & 65535;
      int kb = r >> 11, n = (r >> 3) & 255, j = r & 7;
      int k = kb * 8 + j;
      v = wh[(layer << 16) + k * 256 + n];
    } else {                                  // Whead plain [16][256]
      int rel = i - WHEAD_OFF;
      int n = rel >> 8, k = rel & 255;
      v = (n == 0) ? wd[k] : ((n < 4) ? wc[k * 3 + n - 1] : 0.0f);
    }
    ws[i] = (_Float16)v;
  }
}

// X: k-tiled LDS layout [m/32][k/8][32 m][8 k] fp16 (64 KB), then 8 KB bias.
// byte addr = (m>>5)*16384 + (k>>3)*512 + (m&31)*16 + (k&7)*2
// B-frag reads: 32 lanes contiguous 512 B -> conflict-free.
// Epilogue b64 writes: 16-lane phases at stride 16 B -> 2-way (free).
#define BIAS_LDS 65536  // [8 layer][256 n] float
__device__ __forceinline__ int x2addr(int m, int kb) {  // kb = k/8
  return (m >> 5) * 16384 + kb * 512 + (m & 31) * 16;
}

// One layer: Y[m][n] = act(sum_k W[n][k] X[m][k] + b[n]) for 128 pts.
// Swapped MFMA: A = weights (rows -> n), B = acts (cols -> m), D[n][m].
// 4 waves (1/SIMD): wave w owns n in [w*64,+64) (2 n-tiles), ALL 128 m
// (4 m-tiles). Per ks: 2 A-loads + 4 B ds_reads -> 8 MFMA, 1-deep prefetch.
// setprio(1) around the MFMA cluster (R13 vs R15 A/B: removing it cost
// ~12-25 us; T5 structure-conditional — our load/MFMA role-split qualifies).
// Relu in packed f16 (exact: cvt monotone, cvt(0)=0) — R15: VALUBusy 37->20.
// Bias from LDS; A ks=0 chained across layers (lands at barrier drain).
template <int KB>  // KB = K/16
__device__ __forceinline__ void mlp_layer(char* X, const _Float16* __restrict__ Wt,
                                          const _Float16* __restrict__ Wt_next,
                                          size_t laneoff, int bias_off, bool relu,
                                          int wn, int lr5, int lg2,
                                          half8& a0, half8& a1) {
  const _Float16* wb = Wt + laneoff;
  const _Float16* wbn = Wt_next + laneoff;
  // B-read base: lane lr5 within k-subtile kb = 2*ks + lg2, m-subtile mt
  const int broff = lg2 * 512 + lr5 * 16;  // + mt*16384 + ks*1024

  // fill: B first (ds), bias after (ds, broadcast) -> all overlap
  half8 bc0 = *(const half8*)&X[broff];
  half8 bc1 = *(const half8*)&X[broff + 16384];
  half8 bc2 = *(const half8*)&X[broff + 32768];
  half8 bc3 = *(const half8*)&X[broff + 49152];
  float4v bq[2][4];
#pragma unroll
  for (int nt = 0; nt < 2; ++nt)
#pragma unroll
    for (int q = 0; q < 4; ++q)
      bq[nt][q] = *(const float4v*)&X[bias_off +
                                      (wn * 64 + nt * 32 + q * 8 + lg2 * 4) * 4];

  f32x16 acc[2][4];  // [nt][mt]
#pragma unroll
  for (int nt = 0; nt < 2; ++nt)
#pragma unroll
    for (int q = 0; q < 4; ++q)
#pragma unroll
      for (int mt = 0; mt < 4; ++mt)
#pragma unroll
        for (int rr = 0; rr < 4; ++rr) acc[nt][mt][q * 4 + rr] = bq[nt][q][rr];

#pragma unroll
  for (int ks = 0; ks < KB; ++ks) {
    // prefetch ks+1 (or next layer's ks=0 on the last iteration)
    const _Float16* nb = (ks + 1 < KB) ? (wb + (size_t)(ks + 1) * 4096) : wbn;
    half8 a0n = *(const half8*)nb;
    half8 a1n = *(const half8*)(nb + 256);
    half8 bn0 = bc0, bn1 = bc1, bn2 = bc2, bn3 = bc3;
    if (ks + 1 < KB) {
      const int c = broff + (ks + 1) * 1024;
      bn0 = *(const half8*)&X[c];
      bn1 = *(const half8*)&X[c + 16384];
      bn2 = *(const half8*)&X[c + 32768];
      bn3 = *(const half8*)&X[c + 49152];
    }
    __builtin_amdgcn_s_setprio(1);
    acc[0][0] = __builtin_amdgcn_mfma_f32_32x32x16_f16(a0, bc0, acc[0][0], 0, 0, 0);
    acc[1][0] = __builtin_amdgcn_mfma_f32_32x32x16_f16(a1, bc0, acc[1][0], 0, 0, 0);
    acc[0][1] = __builtin_amdgcn_mfma_f32_32x32x16_f16(a0, bc1, acc[0][1], 0, 0, 0);
    acc[1][1] = __builtin_amdgcn_mfma_f32_32x32x16_f16(a1, bc1, acc[1][1], 0, 0, 0);
    acc[0][2] = __builtin_amdgcn_mfma_f32_32x32x16_f16(a0, bc2, acc[0][2], 0, 0, 0);
    acc[1][2] = __builtin_amdgcn_mfma_f32_32x32x16_f16(a1, bc2, acc[1][2], 0, 0, 0);
    acc[0][3] = __builtin_amdgcn_mfma_f32_32x32x16_f16(a0, bc3, acc[0][3], 0, 0, 0);
    acc[1][3] = __builtin_amdgcn_mfma_f32_32x32x16_f16(a1, bc3, acc[1][3], 0, 0, 0);
    __builtin_amdgcn_s_setprio(0);
    a0 = a0n; a1 = a1n;
    bc0 = bn0; bc1 = bn1; bc2 = bn2; bc3 = bn3;
  }
  __syncthreads();  // all waves done reading X (also drains chained A loads)

  // Epilogue: lane holds D[n = wn*64+nt*32+8q+4lg2+rr][m = mt*32+lr5].
  // cvt to f16 (RNE), relu as packed v_pk_max_f16. 4 consecutive n (rr) = 4
  // consecutive k of next layer -> b64 write at X2[m][k=n]:
  // addr = mt*16384 + (wn*8+nt*4+q)*512 + lr5*16 + lg2*8.
  const half4v zero4 = {(_Float16)0, (_Float16)0, (_Float16)0, (_Float16)0};
#pragma unroll
  for (int mt = 0; mt < 4; ++mt) {
#pragma unroll
    for (int nt = 0; nt < 2; ++nt)
#pragma unroll
      for (int q = 0; q < 4; ++q) {
        half4v hv;
#pragma unroll
        for (int rr = 0; rr < 4; ++rr) hv[rr] = (_Float16)acc[nt][mt][q * 4 + rr];
        if (relu) hv = __builtin_elementwise_max(hv, zero4);
        *(half4v*)&X[mt * 16384 + (wn * 8 + nt * 4 + q) * 512 + lr5 * 16 + lg2 * 8] = hv;
      }
  }
  __syncthreads();  // Y visible as next layer's X
}

__global__ __launch_bounds__(256, 2) void nerf_fused(
    const float* __restrict__ pos, const float* __restrict__ vdir,
    const float* __restrict__ t0, const float* __restrict__ t1,
    const float* __restrict__ t2, const float* __restrict__ t3,
    const float* __restrict__ t4, const float* __restrict__ t5,
    const float* __restrict__ t6, const float* __restrict__ t7,
    const float* __restrict__ b0, const float* __restrict__ bh,
    const float* __restrict__ bd, const float* __restrict__ bc,
    const _Float16* __restrict__ ws, float* __restrict__ out) {
  __shared__ __align__(16) char X[73728];  // 64 KB acts + 8 KB bias
  const int tid = threadIdx.x;
  const int wg = blockIdx.x;
  const int m = tid & 127;
  const int p = wg * 128 + m;

  const int lane = tid & 63;
  const int w = tid >> 6;  // wave 0..3 -> n in [w*64, +64)
  const int lr5 = lane & 31;
  const int lg2 = lane >> 5;
  const size_t laneoff = ((size_t)(lg2 * 256 + w * 64 + lr5)) * 8;

  // chained A preload for layer 0 (completes at the encode barrier)
  half8 a0 = *(const half8*)(ws + W0T_OFF + laneoff);
  half8 a1 = *(const half8*)(ws + W0T_OFF + laneoff + 256);

  // ---------------- encode: 128 points -> X[m][k<96] ----------------
  if (tid < 128) {
    // hash levels 0..7 for point m -> kb = lv
    const float px = pos[p * 3], py = pos[p * 3 + 1], pz = pos[p * 3 + 2];
    const float* tabs[8] = {t0, t1, t2, t3, t4, t5, t6, t7};
    const int resi[8] = {32, 64, 128, 256, 512, 1024, 2048, 2048};
    const float tmax[8] = {32767.0f, 262143.0f, 524287.0f, 524287.0f,
                           524287.0f, 524287.0f, 524287.0f, 524287.0f};
#pragma unroll
    for (int lv = 0; lv < 8; ++lv) {
      const float r = (float)resi[lv];
      const float hr = 0.5f * r;
      const float rm1 = r - 1.0f;
      // replicate numpy fp32 rounding exactly; no FMA contraction
      float cx = fminf(fmaxf(__fmul_rn(__fadd_rn(px, 1.0f), hr), 0.0f), rm1);
      float cy = fminf(fmaxf(__fmul_rn(__fadd_rn(py, 1.0f), hr), 0.0f), rm1);
      float cz = fminf(fmaxf(__fmul_rn(__fadd_rn(pz, 1.0f), hr), 0.0f), rm1);
      float idxf = __fadd_rn(__fadd_rn(__fmul_rn(cx, r * r), __fmul_rn(cy, r)), cz);
      idxf = fminf(fmaxf(idxf, 0.0f), tmax[lv]);
      int idx = (int)idxf;
      const float4* row = (const float4*)(tabs[lv] + (size_t)idx * 8);
      float4 f0 = row[0], f1 = row[1];
      half8 h;
      h[0] = (_Float16)f0.x; h[1] = (_Float16)f0.y;
      h[2] = (_Float16)f0.z; h[3] = (_Float16)f0.w;
      h[4] = (_Float16)f1.x; h[5] = (_Float16)f1.y;
      h[6] = (_Float16)f1.z; h[7] = (_Float16)f1.w;
      *(half8*)&X[x2addr(m, lv)] = h;
    }
  } else {
    // view features k = 64..90 (kb = 8..11), zero pad to 95
    float v0 = vdir[p * 3], v1 = vdir[p * 3 + 1], v2 = vdir[p * 3 + 2];
    const float cf[4] = {(float)(M_PI), (float)(2.0 * M_PI),
                         (float)(4.0 * M_PI), (float)(8.0 * M_PI)};
    float feat[32];
    feat[0] = v0; feat[1] = v1; feat[2] = v2;
    float vv[3] = {v0, v1, v2};
#pragma unroll
    for (int f = 0; f < 4; ++f)
#pragma unroll
      for (int d = 0; d < 3; ++d) {
        float arg = __fmul_rn(cf[f], vv[d]);
        feat[3 + f * 6 + d] = __sinf(arg);
        feat[6 + f * 6 + d] = __cosf(arg);
      }
#pragma unroll
    for (int i = 27; i < 32; ++i) feat[i] = 0.0f;
#pragma unroll
    for (int s = 0; s < 4; ++s) {
      half8 h;
#pragma unroll
      for (int j = 0; j < 8; ++j) h[j] = (_Float16)feat[s * 8 + j];
      *(half8*)&X[x2addr(m, 8 + s)] = h;
    }
  }
  // stage biases into LDS: [8 layer][256 n] float (b0 then bh[0..6])
#pragma unroll
  for (int i = 0; i < 8; ++i) {
    int idx = tid + i * 256;
    float bv = (idx < 256) ? b0[idx] : bh[idx - 256];
    *(float*)&X[BIAS_LDS + idx * 4] = bv;
  }
  __syncthreads();

  // ---------------- MLP ----------------
  mlp_layer<6>(X, ws + W0T_OFF, ws + WHT_OFF, laneoff, BIAS_LDS, true,
               w, lr5, lg2, a0, a1);
#pragma unroll 1
  for (int i = 0; i < 7; ++i) {
    const _Float16* wnext =
        (i < 6) ? (ws + WHT_OFF + ((i + 1) << 16)) : (ws + W0T_OFF);  // last: dummy
    mlp_layer<16>(X, ws + WHT_OFF + (i << 16), wnext, laneoff,
                  BIAS_LDS + (i + 1) * 1024, i < 6, w, lr5, lg2, a0, a1);
  }

  // ------- head (16x16x32, A = acts): wave w -> pts [w*32, +32), 2 m-tiles ----
  const int lr = lane & 15;
  const int lg = lane >> 4;
  float4v hacc[2];
  {
    float bv = (lr == 0) ? bd[0] : ((lr < 4) ? bc[lr - 1] : 0.0f);
    hacc[0] = (float4v){bv, bv, bv, bv};
    hacc[1] = hacc[0];
  }
  const _Float16* Wh = ws + WHEAD_OFF;
#pragma unroll
  for (int ks = 0; ks < 8; ++ks) {
    half8 bfr = *(const half8*)(Wh + lr * 256 + ks * 32 + lg * 8);
#pragma unroll
    for (int mt = 0; mt < 2; ++mt) {
      // A[m = w*32+mt*16+lr][k = ks*32 + lg*8 .. +7] -> kb = ks*4 + lg
      half8 a = *(const half8*)&X[x2addr(w * 32 + mt * 16 + lr, ks * 4 + lg)];
      hacc[mt] = __builtin_amdgcn_mfma_f32_16x16x32_f16(a, bfr, hacc[mt], 0, 0, 0);
    }
  }
#pragma unroll
  for (int mt = 0; mt < 2; ++mt)
#pragma unroll
    for (int r = 0; r < 4; ++r) {
      int pp = wg * 128 + w * 32 + mt * 16 + lg * 4 + r;
      float vv = hacc[mt][r];
      if (lr == 0) {
        out[pp] = vv;  // density
      } else if (lr < 4) {
        out[N_PTS + 3 * pp + (lr - 1)] = 1.0f / (1.0f + __expf(-vv));  // color
      }
    }
}

extern "C" void kernel_launch(void* const* d_in, const int* in_sizes, int n_in,
                              void* d_out, int out_size, void* d_ws, size_t ws_size,
                              hipStream_t stream) {
  const float* pos = (const float*)d_in[0];
  const float* vdir = (const float*)d_in[1];
  const float* t0 = (const float*)d_in[2];
  const float* t1 = (const float*)d_in[3];
  const float* t2 = (const float*)d_in[4];
  const float* t3 = (const float*)d_in[5];
  const float* t4 = (const float*)d_in[6];
  const float* t5 = (const float*)d_in[7];
  const float* t6 = (const float*)d_in[8];
  const float* t7 = (const float*)d_in[9];
  const float* w0 = (const float*)d_in[10];
  const float* b0 = (const float*)d_in[11];
  const float* wh = (const float*)d_in[12];
  const float* bh = (const float*)d_in[13];
  const float* wd = (const float*)d_in[14];
  const float* bd = (const float*)d_in[15];
  const float* wc = (const float*)d_in[16];
  const float* bc = (const float*)d_in[17];
  _Float16* ws = (_Float16*)d_ws;
  float* out = (float*)d_out;

  hipLaunchKernelGGL(prep_weights, dim3((WS_HALVES + 255) / 256), dim3(256), 0, stream,
                     w0, wh, wd, wc, ws);
  hipLaunchKernelGGL(nerf_fused, dim3(N_PTS / 128), dim3(256), 0, stream,
                     pos, vdir, t0, t1, t2, t3, t4, t5, t6, t7,
                     b0, bh, bd, bc, (const _Float16*)ws, out);
}